// Round 4
// baseline (64028.223 us; speedup 1.0000x reference)
//
#include <hip/hip_runtime.h>
#include <hip/hip_bf16.h>

// GridNetBlock round-4.
// DTYPE FACT (established empirically over rounds 0-3): inputs, params, and
// output are ALL FP32. (R0/R3 hard-coded bf16 -> NaN; R1 adaptive -> passed
// via its fp32 paths.) This version is specialized to fp32 throughout; params
// are consumed directly from d_in (no conversion arena).
// Inter-LSTM: 260 blocks x 1024 threads, 1 seq/block, 4-way K-split with LDS
// reduce; recurrent weights pre-transposed to bf16 k-major (halves L2 bytes).
// B=4 T=512 NF=65 C=128 NH=4 E=8 H=256 DOWN=4 L=100 VD=32.
//
// ws layout (bytes):
//  A [0,68.2M):        hc[16.8M]+yf[33.5M]  ->  ln1y -> Vh -> ph
//  B [68.2M,136.3M):   intra -> av
//  C [136.3M,204.5M):  inter
//  DE[204.5M,238.6M):  yr[33.5M] -> Qh[17M]+Kh[17M]
//  WT[238.6M,242.5M):  fp32 transposed intra weights + bf16 inter weights

typedef unsigned short u16;
typedef unsigned int u32;

#define OFF_A    0ULL
#define OFF_B    68157440ULL
#define OFF_C    136314880ULL
#define OFF_DE   204472320ULL
#define OFF_WT   238551040ULL

__device__ __forceinline__ float b2f(u16 u) {
  union { u32 i; float f; } v; v.i = ((u32)u) << 16; return v.f;
}
__device__ __forceinline__ float sigf(float x) { return 1.f / (1.f + __expf(-x)); }
__device__ __forceinline__ float tanh_(float x) {
  float cx = fminf(15.f, fmaxf(-15.f, x));
  float e = __expf(2.f * cx);
  return (e - 1.f) / (e + 1.f);
}
__device__ __forceinline__ void wavered2(float& s, float& q) {
  #pragma unroll
  for (int o = 32; o > 0; o >>= 1) {
    s += __shfl_down(s, o, 64);
    q += __shfl_down(q, o, 64);
  }
}

// ---------------- transpose fp32 [R][K] -> fp32 [K][R] ----------------
__global__ void k_transpose_ff(const float* __restrict__ src, float* __restrict__ dst,
                               int R, int K) {
  int e = blockIdx.x * 256 + threadIdx.x;
  if (e >= R * K) return;
  int r = e / K, k = e - r * K;
  dst[k * R + r] = src[e];
}

// ---------------- transpose fp32 [R][K] -> bf16 [K][R] ----------------
__global__ void k_transpose_fb(const float* __restrict__ src, u16* __restrict__ dst,
                               int R, int K) {
  int e = blockIdx.x * 256 + threadIdx.x;
  if (e >= R * K) return;
  int r = e / K, k = e - r * K;
  __hip_bfloat16 h = __float2bfloat16(src[e]);
  dst[k * R + r] = *(u16*)&h;
}

// ---------------- conv(k=s=4) + bias + PReLU + LN(C) ----------------
__global__ __launch_bounds__(256) void k_conv_ln0(
    const float* __restrict__ x32, const float* __restrict__ cw,
    const float* __restrict__ cb, const float* __restrict__ ca,
    const float* __restrict__ g0, const float* __restrict__ b0,
    float* __restrict__ hc) {
  __shared__ float xs[8192];   // [64 freq][128 c]
  __shared__ float hs[2048];   // [16][128]
  __shared__ float mu_[16], ri_[16];
  int n = blockIdx.x, tid = threadIdx.x;
  const float4* xr = (const float4*)(x32 + (size_t)n * 8320);
  for (int e = tid; e < 2048; e += 256) ((float4*)xs)[e] = xr[e];
  __syncthreads();
  int g = tid >> 7, o = tid & 127;
  float a = ca[0];
  float cbv = cb[o];
  float acc[8];
  #pragma unroll
  for (int j = 0; j < 8; ++j) acc[j] = cbv;
  const float4* cw4 = (const float4*)cw;   // [o][c][4m]
  for (int c = 0; c < 128; ++c) {
    float4 w = cw4[o * 128 + c];
    #pragma unroll
    for (int j = 0; j < 8; ++j) {
      int i = 8 * g + j;
      const float* xi = &xs[i * 512 + c];
      acc[j] += w.x * xi[0] + w.y * xi[128] + w.z * xi[256] + w.w * xi[384];
    }
  }
  #pragma unroll
  for (int j = 0; j < 8; ++j) {
    int i = 8 * g + j;
    float v = acc[j];
    v = v >= 0.f ? v : a * v;
    hs[i * 128 + o] = v;
  }
  __syncthreads();
  if (tid < 16) {
    float s = 0.f, q = 0.f;
    for (int c = 0; c < 128; ++c) { float v = hs[tid * 128 + c]; s += v; q += v * v; }
    float mu = s / 128.f;
    mu_[tid] = mu;
    ri_[tid] = rsqrtf(fmaxf(q / 128.f - mu * mu, 0.f) + 1e-5f);
  }
  __syncthreads();
  float gg = g0[o], bb = b0[o];
  #pragma unroll
  for (int j = 0; j < 8; ++j) {
    int i = 8 * g + j;
    hc[((size_t)n * 16 + i) * 128 + o] = (hs[i * 128 + o] - mu_[i]) * ri_[i] * gg + bb;
  }
}

// ---------------- intra BiLSTM over freq (seq len 16) ----------------
__global__ __launch_bounds__(256) void k_intra_lstm(
    const float* __restrict__ hc,
    const float* __restrict__ wiTf, const float* __restrict__ whTf,
    const float* __restrict__ bihf, const float* __restrict__ bhhf,
    const float* __restrict__ wiTr, const float* __restrict__ whTr,
    const float* __restrict__ bihr, const float* __restrict__ bhhr,
    float* __restrict__ yf, float* __restrict__ yr) {
  __shared__ float xt[1024];    // [8][128]
  __shared__ float hsh[2048];   // [8][256]
  __shared__ float csh[2048];
  __shared__ float gbuf[8192];  // [8][1024]
  int tid = threadIdx.x;
  int grp = blockIdx.x & 255, dir = blockIdx.x >> 8;
  int n0 = grp * 8;
  const float4* wi4 = (const float4*)(dir ? wiTr : wiTf);
  const float4* wh4 = (const float4*)(dir ? whTr : whTf);
  const float* bi = dir ? bihr : bihf;
  const float* bh = dir ? bhhr : bhhf;
  float* yo = dir ? yr : yf;
  float bias[4];
  #pragma unroll
  for (int j = 0; j < 4; ++j) bias[j] = bi[4 * tid + j] + bh[4 * tid + j];
  for (int e = tid; e < 2048; e += 256) { hsh[e] = 0.f; csh[e] = 0.f; }
  for (int t = 0; t < 16; ++t) {
    int tt = dir ? 15 - t : t;
    for (int e = tid; e < 1024; e += 256)
      xt[e] = hc[((size_t)(n0 + (e >> 7)) * 16 + tt) * 128 + (e & 127)];
    __syncthreads();
    float acc[4][8];
    #pragma unroll
    for (int j = 0; j < 4; ++j)
      #pragma unroll
      for (int s = 0; s < 8; ++s) acc[j][s] = bias[j];
    for (int k = 0; k < 128; ++k) {
      float4 w = wi4[k * 256 + tid];
      #pragma unroll
      for (int s = 0; s < 8; ++s) {
        float xv = xt[s * 128 + k];
        acc[0][s] += w.x * xv; acc[1][s] += w.y * xv;
        acc[2][s] += w.z * xv; acc[3][s] += w.w * xv;
      }
    }
    for (int k = 0; k < 256; ++k) {
      float4 w = wh4[k * 256 + tid];
      #pragma unroll
      for (int s = 0; s < 8; ++s) {
        float hv = hsh[s * 256 + k];
        acc[0][s] += w.x * hv; acc[1][s] += w.y * hv;
        acc[2][s] += w.z * hv; acc[3][s] += w.w * hv;
      }
    }
    #pragma unroll
    for (int j = 0; j < 4; ++j)
      #pragma unroll
      for (int s = 0; s < 8; ++s)
        gbuf[s * 1024 + 4 * tid + j] = acc[j][s];
    __syncthreads();
    #pragma unroll
    for (int s = 0; s < 8; ++s) {
      float iv = gbuf[s * 1024 + tid];
      float fv = gbuf[s * 1024 + 256 + tid];
      float gv = gbuf[s * 1024 + 512 + tid];
      float ov = gbuf[s * 1024 + 768 + tid];
      float cn = sigf(fv) * csh[s * 256 + tid] + sigf(iv) * tanh_(gv);
      float hn = sigf(ov) * tanh_(cn);
      csh[s * 256 + tid] = cn;
      hsh[s * 256 + tid] = hn;
      yo[((size_t)(n0 + s) * 16 + tt) * 256 + tid] = hn;   // stored at ORIGINAL pos
    }
    __syncthreads();
  }
}

// ---------------- deconv(k=s=4) + bias + pad + residual ----------------
__global__ __launch_bounds__(256) void k_deconv(
    const float* __restrict__ yf, const float* __restrict__ yr,
    const float* __restrict__ dw, const float* __restrict__ db,
    const float* __restrict__ x32, float* __restrict__ intra) {
  __shared__ float hbi[8192];   // [16][512]
  int n = blockIdx.x, tid = threadIdx.x;
  for (int e = tid; e < 8192; e += 256) {
    int i = e >> 9, d = e & 511;
    hbi[e] = d < 256 ? yf[((size_t)n * 16 + i) * 256 + d]
                     : yr[((size_t)n * 16 + i) * 256 + d - 256];
  }
  __syncthreads();
  int op0 = tid, op1 = tid + 256;   // op = o*4 + m
  float acc0[16], acc1[16];
  #pragma unroll
  for (int i = 0; i < 16; ++i) { acc0[i] = 0.f; acc1[i] = 0.f; }
  for (int d = 0; d < 512; d += 2) {
    float w00 = dw[(size_t)d * 512 + op0];
    float w01 = dw[(size_t)d * 512 + op1];
    float w10 = dw[(size_t)(d + 1) * 512 + op0];
    float w11 = dw[(size_t)(d + 1) * 512 + op1];
    #pragma unroll
    for (int i = 0; i < 16; ++i) {
      float2 hv = *(const float2*)&hbi[i * 512 + d];
      acc0[i] += hv.x * w00 + hv.y * w10;
      acc1[i] += hv.x * w01 + hv.y * w11;
    }
  }
  int o0 = op0 >> 2, m0 = op0 & 3, o1 = op1 >> 2, m1 = op1 & 3;
  float db0 = db[o0], db1 = db[o1];
  #pragma unroll
  for (int i = 0; i < 16; ++i) {
    size_t i0 = ((size_t)n * 65 + i * 4 + m0) * 128 + o0;
    size_t i1 = ((size_t)n * 65 + i * 4 + m1) * 128 + o1;
    intra[i0] = acc0[i] + db0 + x32[i0];
    intra[i1] = acc1[i] + db1 + x32[i1];
  }
  if (tid < 128) {   // padded freq row 64: zeros + bias + residual
    size_t ip = ((size_t)n * 65 + 64) * 128 + tid;
    intra[ip] = db[tid] + x32[ip];
  }
}

// ---------------- LN over C + transpose to [B*NF][T][C] ----------------
__global__ __launch_bounds__(256) void k_ln1(
    const float* __restrict__ intra, const float* __restrict__ g1,
    const float* __restrict__ b1, float* __restrict__ out) {
  __shared__ float rs[4], rq[4];
  int n = blockIdx.x, tid = threadIdx.x;
  int gr = tid >> 7, o = tid & 127, wid = tid >> 6;
  int b = n >> 9, t = n & 511;
  float gv = g1[o], bv = b1[o];
  for (int f0 = 0; f0 < 65; f0 += 2) {
    int f = f0 + gr;
    bool ok = f < 65;
    float v = 0.f;
    if (ok) v = intra[((size_t)n * 65 + f) * 128 + o];
    float s = v, q = v * v;
    wavered2(s, q);
    if ((tid & 63) == 0) { rs[wid] = s; rq[wid] = q; }
    __syncthreads();
    if (ok) {
      float S = rs[2 * gr] + rs[2 * gr + 1], Q = rq[2 * gr] + rq[2 * gr + 1];
      float mu = S / 128.f;
      float rinv = rsqrtf(fmaxf(Q / 128.f - mu * mu, 0.f) + 1e-5f);
      out[((size_t)(b * 65 + f) * 512 + t) * 128 + o] = (v - mu) * rinv * gv + bv;
    }
    __syncthreads();
  }
}

// ---------------- inter causal LSTM over time + fused Linear + residual ----
// 260 blocks x 1024 threads, ONE sequence per block.
// 4-way K-split: group g (256 threads) computes partial gates over x-k slice
// [g*32,g*32+32) and h-k slice [g*64,g*64+64); LDS reduce; bf16 weights.
__global__ __launch_bounds__(1024) void k_inter_lstm(
    const float* __restrict__ ln1y,
    const u16* __restrict__ wiTb, const u16* __restrict__ whTb,
    const float* __restrict__ bih, const float* __restrict__ bhh,
    const float* __restrict__ lw, const float* __restrict__ lb,
    const float* __restrict__ h0a, const float* __restrict__ c0a,
    const float* __restrict__ intra, float* __restrict__ inter) {
  __shared__ float xt[128];
  __shared__ float hsh[256];
  __shared__ float csh[256];
  __shared__ float pb[4][1024];   // gate partials; pb[0] reused as lin scratch
  int tid = threadIdx.x;
  int n = blockIdx.x;             // sequence 0..259
  int b_l = n / 65, f_l = n - b_l * 65;
  if (tid < 256) {
    hsh[tid] = h0a[(size_t)n * 256 + tid];
    csh[tid] = c0a[(size_t)n * 256 + tid];
  }
  int g = tid >> 8, l = tid & 255;
  float bi_i = 0.f, bi_f = 0.f, bi_g = 0.f, bi_o = 0.f;
  if (tid < 256) {
    bi_i = bih[tid] + bhh[tid];
    bi_f = bih[256 + tid] + bhh[256 + tid];
    bi_g = bih[512 + tid] + bhh[512 + tid];
    bi_o = bih[768 + tid] + bhh[768 + tid];
  }
  float linb = (tid < 128) ? lb[tid] : 0.f;
  const u16* wip = wiTb + (size_t)(g * 32) * 1024 + 4 * l;
  const u16* whp = whTb + (size_t)(g * 64) * 1024 + 4 * l;
  const float* xsrc = ln1y + (size_t)n * 65536;
  // phase-4a mapping: channel ci, k-slice part
  int ci = tid >> 3, part = tid & 7;
  const float4* lr4 = (const float4*)(lw + (size_t)ci * 256 + part * 32);
  __syncthreads();
  for (int t = 0; t < 512; ++t) {
    // P1: stage x_t, prefetch residual
    if (tid < 128) xt[tid] = xsrc[(size_t)t * 128 + tid];
    float resid = 0.f;
    size_t oi = 0;
    if (tid < 128) {
      oi = ((size_t)(b_l * 512 + t) * 65 + f_l) * 128 + tid;
      resid = intra[oi];
    }
    __syncthreads();
    // P2: partial gate dot products over this group's k-slice
    float a0 = 0.f, a1 = 0.f, a2 = 0.f, a3 = 0.f;
    for (int k = 0; k < 32; ++k) {
      ushort4 u = *(const ushort4*)(wip + (size_t)k * 1024);
      float xv = xt[g * 32 + k];
      a0 += b2f(u.x) * xv; a1 += b2f(u.y) * xv;
      a2 += b2f(u.z) * xv; a3 += b2f(u.w) * xv;
    }
    for (int k = 0; k < 64; ++k) {
      ushort4 u = *(const ushort4*)(whp + (size_t)k * 1024);
      float hv = hsh[g * 64 + k];
      a0 += b2f(u.x) * hv; a1 += b2f(u.y) * hv;
      a2 += b2f(u.z) * hv; a3 += b2f(u.w) * hv;
    }
    pb[g][4 * l]     = a0;
    pb[g][4 * l + 1] = a1;
    pb[g][4 * l + 2] = a2;
    pb[g][4 * l + 3] = a3;
    __syncthreads();
    // P3: reduce partials, gate nonlinearities, state update
    if (tid < 256) {
      float iv = bi_i + pb[0][tid] + pb[1][tid] + pb[2][tid] + pb[3][tid];
      float fv = bi_f + pb[0][256 + tid] + pb[1][256 + tid] + pb[2][256 + tid] + pb[3][256 + tid];
      float gv = bi_g + pb[0][512 + tid] + pb[1][512 + tid] + pb[2][512 + tid] + pb[3][512 + tid];
      float ov = bi_o + pb[0][768 + tid] + pb[1][768 + tid] + pb[2][768 + tid] + pb[3][768 + tid];
      float cn = sigf(fv) * csh[tid] + sigf(iv) * tanh_(gv);
      float hn = sigf(ov) * tanh_(cn);
      csh[tid] = cn;
      hsh[tid] = hn;
    }
    __syncthreads();
    // P4a: fused Linear partials (all threads; 32 k each)
    {
      const float* hk = hsh + part * 32;
      float acc = 0.f;
      #pragma unroll
      for (int qq = 0; qq < 8; ++qq) {
        float4 w = lr4[qq];
        acc += w.x * hk[4 * qq] + w.y * hk[4 * qq + 1]
             + w.z * hk[4 * qq + 2] + w.w * hk[4 * qq + 3];
      }
      pb[0][tid] = acc;   // pb dead after P3; safe to reuse
    }
    __syncthreads();
    // P4b: combine partials + residual store
    if (tid < 128) {
      float acc = linb + resid;
      #pragma unroll
      for (int p = 0; p < 8; ++p) acc += pb[0][tid * 8 + p];
      inter[oi] = acc;
    }
    __syncthreads();
  }
}

// ---------------- Q/K/V projections + PReLU (pre-LN) ----------------
__global__ __launch_bounds__(256) void k_qkv(
    const float* __restrict__ inter,
    const float* __restrict__ qw, const float* __restrict__ qb, const float* __restrict__ qa,
    const float* __restrict__ kw, const float* __restrict__ kb, const float* __restrict__ ka,
    const float* __restrict__ vw, const float* __restrict__ vb, const float* __restrict__ va,
    float* __restrict__ Qh, float* __restrict__ Kh, float* __restrict__ Vh) {
  __shared__ float xsl[8320];
  int n = blockIdx.x, tid = threadIdx.x;
  int b = n >> 9, t = n & 511;
  for (int e = tid; e < 8320; e += 256) xsl[e] = inter[(size_t)n * 8320 + e];
  __syncthreads();
  if (tid >= 192) return;
  const float* wrow; float bias, a; float* dst; int dsz;
  if (tid < 32) {
    wrow = qw + (size_t)tid * 128; bias = qb[tid]; a = qa[0];
    dst = Qh + ((size_t)(b * 4 + (tid >> 3)) * 512 + t) * 520 + (tid & 7); dsz = 8;
  } else if (tid < 64) {
    int d = tid - 32;
    wrow = kw + (size_t)d * 128; bias = kb[d]; a = ka[0];
    dst = Kh + ((size_t)(b * 4 + (d >> 3)) * 512 + t) * 520 + (d & 7); dsz = 8;
  } else {
    int d = tid - 64;
    wrow = vw + (size_t)d * 128; bias = vb[d]; a = va[0];
    dst = Vh + ((size_t)(b * 4 + (d >> 5)) * 512 + t) * 2080 + (d & 31); dsz = 32;
  }
  const float4* w4 = (const float4*)wrow;
  for (int f = 0; f < 65; ++f) {
    float acc = bias;
    const float4* xr = (const float4*)&xsl[f * 128];
    #pragma unroll
    for (int kk = 0; kk < 32; ++kk) {
      float4 w = w4[kk], xv = xr[kk];
      acc += w.x * xv.x + w.y * xv.y + w.z * xv.z + w.w * xv.w;
    }
    acc = acc >= 0.f ? acc : a * acc;
    dst[(size_t)f * dsz] = acc;
  }
}

// ---------------- LN over last dim (in-place) ----------------
__global__ __launch_bounds__(256) void k_lnrow(
    float* __restrict__ buf, int len,
    const float* __restrict__ g, const float* __restrict__ b) {
  __shared__ float rs[4], rq[4];
  int row = blockIdx.x, tid = threadIdx.x;
  float* p = buf + (size_t)row * len;
  float s = 0.f, q = 0.f;
  for (int e = tid; e < len; e += 256) { float v = p[e]; s += v; q += v * v; }
  wavered2(s, q);
  if ((tid & 63) == 0) { rs[tid >> 6] = s; rq[tid >> 6] = q; }
  __syncthreads();
  float S = rs[0] + rs[1] + rs[2] + rs[3];
  float Q = rq[0] + rq[1] + rq[2] + rq[3];
  float mu = S / len;
  float rinv = rsqrtf(fmaxf(Q / len - mu * mu, 0.f) + 1e-5f);
  for (int e = tid; e < len; e += 256) {
    float v = p[e];
    p[e] = (v - mu) * rinv * g[e] + b[e];
  }
}

// ---------------- windowed causal attention (100 keys) ----------------
__global__ __launch_bounds__(256) void k_attn(
    const float* __restrict__ Qh, const float* __restrict__ Kh,
    const float* __restrict__ Vh, const float* __restrict__ Kbuf,
    const float* __restrict__ Vbuf, float* __restrict__ av) {
  __shared__ float qrow[520], sc[100], red[2];
  int bid = blockIdx.x, tid = threadIdx.x;
  int bh = bid >> 9, t = bid & 511;
  for (int e = tid; e < 520; e += 256)
    qrow[e] = Qh[((size_t)bh * 512 + t) * 520 + e];
  __syncthreads();
  if (tid < 100) {
    int s = t + tid;
    float acc = 0.f;
    if (s < 99) {
      const float* kr = Kbuf + ((size_t)bh * 99 + s) * 520;
      for (int e = 0; e < 520; ++e) acc += qrow[e] * kr[e];
    } else {
      const float* kr = Kh + ((size_t)bh * 512 + (s - 99)) * 520;
      for (int e = 0; e < 520; ++e) acc += qrow[e] * kr[e];
    }
    sc[tid] = acc * 0.04385290096535147f;   // 1/sqrt(520)
  }
  __syncthreads();
  if (tid == 0) {
    float m = sc[0];
    for (int k = 1; k < 100; ++k) m = fmaxf(m, sc[k]);
    red[0] = m;
  }
  __syncthreads();
  if (tid < 100) sc[tid] = __expf(sc[tid] - red[0]);
  __syncthreads();
  if (tid == 0) {
    float s = 0.f;
    for (int k = 0; k < 100; ++k) s += sc[k];
    red[1] = 1.f / s;
  }
  __syncthreads();
  float rscale = red[1];
  int b = bh >> 2, nh = bh & 3;
  int kb = t < 99 ? 99 - t : 0;
  for (int o = tid; o < 2080; o += 256) {
    float acc = 0.f;
    for (int k = 0; k < kb; ++k)
      acc += sc[k] * Vbuf[((size_t)bh * 99 + t + k) * 2080 + o];
    for (int k = kb; k < 100; ++k)
      acc += sc[k] * Vh[((size_t)bh * 512 + (t + k - 99)) * 2080 + o];
    int f = o >> 5, vd = o & 31;
    av[((size_t)(b * 512 + t) * 65 + f) * 128 + nh * 32 + vd] = acc * rscale;
  }
}

// ---------------- P projection + PReLU ----------------
__global__ __launch_bounds__(256) void k_pproj(
    const float* __restrict__ av, const float* __restrict__ pw,
    const float* __restrict__ pb, const float* __restrict__ pa,
    float* __restrict__ ph) {
  __shared__ float avs[8320];
  int n = blockIdx.x, tid = threadIdx.x;
  for (int e = tid; e < 8320; e += 256) avs[e] = av[(size_t)n * 8320 + e];
  __syncthreads();
  int o = tid & 127, g = tid >> 7;
  float a = pa[0], bias = pb[o];
  const float4* w4 = (const float4*)(pw + (size_t)o * 128);
  for (int f = g; f < 65; f += 2) {
    float acc = bias;
    const float4* xr = (const float4*)&avs[f * 128];
    #pragma unroll
    for (int kk = 0; kk < 32; ++kk) {
      float4 w = w4[kk], xv = xr[kk];
      acc += w.x * xv.x + w.y * xv.y + w.z * xv.z + w.w * xv.w;
    }
    acc = acc >= 0.f ? acc : a * acc;
    ph[(size_t)n * 8320 + f * 128 + o] = acc;
  }
}

// ---------------- final LN(8320) + residual -> fp32 out ----------------
__global__ __launch_bounds__(256) void k_lnfinal(
    const float* __restrict__ ph, const float* __restrict__ plg,
    const float* __restrict__ plb, const float* __restrict__ inter,
    float* __restrict__ out) {
  __shared__ float rs[4], rq[4];
  int n = blockIdx.x, tid = threadIdx.x;
  const float* p = ph + (size_t)n * 8320;
  float s = 0.f, q = 0.f;
  for (int e = tid; e < 8320; e += 256) { float v = p[e]; s += v; q += v * v; }
  wavered2(s, q);
  if ((tid & 63) == 0) { rs[tid >> 6] = s; rq[tid >> 6] = q; }
  __syncthreads();
  float S = rs[0] + rs[1] + rs[2] + rs[3];
  float Q = rq[0] + rq[1] + rq[2] + rq[3];
  float mu = S / 8320.f;
  float rinv = rsqrtf(fmaxf(Q / 8320.f - mu * mu, 0.f) + 1e-5f);
  for (int e = tid; e < 8320; e += 256) {
    out[(size_t)n * 8320 + e] =
        (p[e] - mu) * rinv * plg[e] + plb[e] + inter[(size_t)n * 8320 + e];
  }
}

extern "C" void kernel_launch(void* const* d_in, const int* in_sizes, int n_in,
                              void* d_out, int out_size, void* d_ws, size_t ws_size,
                              hipStream_t stream) {
  const float* x       = (const float*)d_in[0];
  const float* conv_w  = (const float*)d_in[1];
  const float* conv_b  = (const float*)d_in[2];
  const float* conv_a  = (const float*)d_in[3];
  const float* ln0_g   = (const float*)d_in[4];
  const float* ln0_b   = (const float*)d_in[5];
  const float* iwih_f  = (const float*)d_in[6];
  const float* iwhh_f  = (const float*)d_in[7];
  const float* ibih_f  = (const float*)d_in[8];
  const float* ibhh_f  = (const float*)d_in[9];
  const float* iwih_r  = (const float*)d_in[10];
  const float* iwhh_r  = (const float*)d_in[11];
  const float* ibih_r  = (const float*)d_in[12];
  const float* ibhh_r  = (const float*)d_in[13];
  const float* deconv_w= (const float*)d_in[14];
  const float* deconv_b= (const float*)d_in[15];
  const float* ln1_g   = (const float*)d_in[16];
  const float* ln1_b   = (const float*)d_in[17];
  const float* wih     = (const float*)d_in[18];
  const float* whh     = (const float*)d_in[19];
  const float* bih     = (const float*)d_in[20];
  const float* bhh     = (const float*)d_in[21];
  const float* lin_w   = (const float*)d_in[22];
  const float* lin_b   = (const float*)d_in[23];
  const float* q_w     = (const float*)d_in[24];
  const float* q_b     = (const float*)d_in[25];
  const float* q_a     = (const float*)d_in[26];
  const float* q_lg    = (const float*)d_in[27];
  const float* q_lb    = (const float*)d_in[28];
  const float* k_w     = (const float*)d_in[29];
  const float* k_b     = (const float*)d_in[30];
  const float* k_a     = (const float*)d_in[31];
  const float* k_lg    = (const float*)d_in[32];
  const float* k_lb    = (const float*)d_in[33];
  const float* v_w     = (const float*)d_in[34];
  const float* v_b     = (const float*)d_in[35];
  const float* v_a     = (const float*)d_in[36];
  const float* v_lg    = (const float*)d_in[37];
  const float* v_lb    = (const float*)d_in[38];
  const float* p_w     = (const float*)d_in[39];
  const float* p_b     = (const float*)d_in[40];
  const float* p_a     = (const float*)d_in[41];
  const float* p_lg    = (const float*)d_in[42];
  const float* p_lb    = (const float*)d_in[43];
  const float* K_buf   = (const float*)d_in[44];
  const float* V_buf   = (const float*)d_in[45];
  const float* h0v     = (const float*)d_in[46];
  const float* c0v     = (const float*)d_in[47];

  char* ws = (char*)d_ws;
  float* hc    = (float*)(ws + OFF_A);
  float* yfb   = (float*)(ws + OFF_A + 16777216ULL);
  float* yrb   = (float*)(ws + OFF_DE);
  float* ln1y  = (float*)(ws + OFF_A);
  float* Vh    = (float*)(ws + OFF_A);
  float* phb   = (float*)(ws + OFF_A);
  float* intra = (float*)(ws + OFF_B);
  float* avb   = (float*)(ws + OFF_B);
  float* inter = (float*)(ws + OFF_C);
  float* Qh    = (float*)(ws + OFF_DE);
  float* Kh    = (float*)(ws + OFF_DE + 17039360ULL);
  float* wT    = (float*)(ws + OFF_WT);
  float* wiTf = wT + 0;        // 131072 floats
  float* whTf = wT + 131072;   // 262144
  float* wiTr = wT + 393216;   // 131072
  float* whTr = wT + 524288;   // 262144 -> ends at 786432 floats (3 MB)
  u16* wiTb = (u16*)(wT + 786432);      // 131072 u16 (256 KB)
  u16* whTb = wiTb + 131072;            // 262144 u16 (512 KB)

  k_transpose_ff<<<512, 256, 0, stream>>>(iwih_f, wiTf, 1024, 128);
  k_transpose_ff<<<1024, 256, 0, stream>>>(iwhh_f, whTf, 1024, 256);
  k_transpose_ff<<<512, 256, 0, stream>>>(iwih_r, wiTr, 1024, 128);
  k_transpose_ff<<<1024, 256, 0, stream>>>(iwhh_r, whTr, 1024, 256);
  k_transpose_fb<<<512, 256, 0, stream>>>(wih, wiTb, 1024, 128);
  k_transpose_fb<<<1024, 256, 0, stream>>>(whh, whTb, 1024, 256);

  k_conv_ln0<<<2048, 256, 0, stream>>>(x, conv_w, conv_b, conv_a, ln0_g, ln0_b, hc);
  k_intra_lstm<<<512, 256, 0, stream>>>(hc, wiTf, whTf, ibih_f, ibhh_f,
                                        wiTr, whTr, ibih_r, ibhh_r, yfb, yrb);
  k_deconv<<<2048, 256, 0, stream>>>(yfb, yrb, deconv_w, deconv_b, x, intra);
  k_ln1<<<2048, 256, 0, stream>>>(intra, ln1_g, ln1_b, ln1y);
  k_inter_lstm<<<260, 1024, 0, stream>>>(ln1y, wiTb, whTb, bih, bhh,
                                         lin_w, lin_b, h0v, c0v, intra, inter);
  k_qkv<<<2048, 256, 0, stream>>>(inter, q_w, q_b, q_a, k_w, k_b, k_a,
                                  v_w, v_b, v_a, Qh, Kh, Vh);
  k_lnrow<<<8192, 256, 0, stream>>>(Qh, 520, q_lg, q_lb);
  k_lnrow<<<8192, 256, 0, stream>>>(Kh, 520, k_lg, k_lb);
  k_lnrow<<<8192, 256, 0, stream>>>(Vh, 2080, v_lg, v_lb);
  k_attn<<<8192, 256, 0, stream>>>(Qh, Kh, Vh, K_buf, V_buf, avb);
  k_pproj<<<2048, 256, 0, stream>>>(avb, p_w, p_b, p_a, phb);
  k_lnfinal<<<2048, 256, 0, stream>>>(phb, p_lg, p_lb, inter, (float*)d_out);
}

// Round 5
// 12395.201 us; speedup vs baseline: 5.1656x; 5.1656x over previous
//
#include <hip/hip_runtime.h>
#include <hip/hip_bf16.h>

// GridNetBlock round-5. dtypes: ALL FP32 (established R0-R4).
// Change vs R4 (one kernel): k_inter_lstm
//  - __launch_bounds__(1024, 4): 1 block/CU, 128-VGPR budget -> no scratch
//    spills (R4: VGPR=64 cap caused ~345 MB spill traffic that thrashed the
//    per-XCD L2 and made the 768 KB weight hot-set miss -> 85 GB L3 fetch).
//  - 2 sequences/block (130 blocks): weight demand 105 GB -> 52 GB.
//  - 4-way K-split retained; fused Linear partials across all 1024 threads.
// B=4 T=512 NF=65 C=128 NH=4 E=8 H=256 DOWN=4 L=100 VD=32.
//
// ws layout (bytes):
//  A [0,68.2M):        hc[16.8M]+yf[33.5M]  ->  ln1y -> Vh -> ph
//  B [68.2M,136.3M):   intra -> av
//  C [136.3M,204.5M):  inter
//  DE[204.5M,238.6M):  yr[33.5M] -> Qh[17M]+Kh[17M]
//  WT[238.6M,242.5M):  fp32 transposed intra weights + bf16 inter weights

typedef unsigned short u16;
typedef unsigned int u32;

#define OFF_A    0ULL
#define OFF_B    68157440ULL
#define OFF_C    136314880ULL
#define OFF_DE   204472320ULL
#define OFF_WT   238551040ULL

__device__ __forceinline__ float b2f(u16 u) {
  union { u32 i; float f; } v; v.i = ((u32)u) << 16; return v.f;
}
__device__ __forceinline__ float sigf(float x) { return 1.f / (1.f + __expf(-x)); }
__device__ __forceinline__ float tanh_(float x) {
  float cx = fminf(15.f, fmaxf(-15.f, x));
  float e = __expf(2.f * cx);
  return (e - 1.f) / (e + 1.f);
}
__device__ __forceinline__ void wavered2(float& s, float& q) {
  #pragma unroll
  for (int o = 32; o > 0; o >>= 1) {
    s += __shfl_down(s, o, 64);
    q += __shfl_down(q, o, 64);
  }
}

// ---------------- transpose fp32 [R][K] -> fp32 [K][R] ----------------
__global__ void k_transpose_ff(const float* __restrict__ src, float* __restrict__ dst,
                               int R, int K) {
  int e = blockIdx.x * 256 + threadIdx.x;
  if (e >= R * K) return;
  int r = e / K, k = e - r * K;
  dst[k * R + r] = src[e];
}

// ---------------- transpose fp32 [R][K] -> bf16 [K][R] ----------------
__global__ void k_transpose_fb(const float* __restrict__ src, u16* __restrict__ dst,
                               int R, int K) {
  int e = blockIdx.x * 256 + threadIdx.x;
  if (e >= R * K) return;
  int r = e / K, k = e - r * K;
  __hip_bfloat16 h = __float2bfloat16(src[e]);
  dst[k * R + r] = *(u16*)&h;
}

// ---------------- conv(k=s=4) + bias + PReLU + LN(C) ----------------
__global__ __launch_bounds__(256) void k_conv_ln0(
    const float* __restrict__ x32, const float* __restrict__ cw,
    const float* __restrict__ cb, const float* __restrict__ ca,
    const float* __restrict__ g0, const float* __restrict__ b0,
    float* __restrict__ hc) {
  __shared__ float xs[8192];   // [64 freq][128 c]
  __shared__ float hs[2048];   // [16][128]
  __shared__ float mu_[16], ri_[16];
  int n = blockIdx.x, tid = threadIdx.x;
  const float4* xr = (const float4*)(x32 + (size_t)n * 8320);
  for (int e = tid; e < 2048; e += 256) ((float4*)xs)[e] = xr[e];
  __syncthreads();
  int g = tid >> 7, o = tid & 127;
  float a = ca[0];
  float cbv = cb[o];
  float acc[8];
  #pragma unroll
  for (int j = 0; j < 8; ++j) acc[j] = cbv;
  const float4* cw4 = (const float4*)cw;   // [o][c][4m]
  for (int c = 0; c < 128; ++c) {
    float4 w = cw4[o * 128 + c];
    #pragma unroll
    for (int j = 0; j < 8; ++j) {
      int i = 8 * g + j;
      const float* xi = &xs[i * 512 + c];
      acc[j] += w.x * xi[0] + w.y * xi[128] + w.z * xi[256] + w.w * xi[384];
    }
  }
  #pragma unroll
  for (int j = 0; j < 8; ++j) {
    int i = 8 * g + j;
    float v = acc[j];
    v = v >= 0.f ? v : a * v;
    hs[i * 128 + o] = v;
  }
  __syncthreads();
  if (tid < 16) {
    float s = 0.f, q = 0.f;
    for (int c = 0; c < 128; ++c) { float v = hs[tid * 128 + c]; s += v; q += v * v; }
    float mu = s / 128.f;
    mu_[tid] = mu;
    ri_[tid] = rsqrtf(fmaxf(q / 128.f - mu * mu, 0.f) + 1e-5f);
  }
  __syncthreads();
  float gg = g0[o], bb = b0[o];
  #pragma unroll
  for (int j = 0; j < 8; ++j) {
    int i = 8 * g + j;
    hc[((size_t)n * 16 + i) * 128 + o] = (hs[i * 128 + o] - mu_[i]) * ri_[i] * gg + bb;
  }
}

// ---------------- intra BiLSTM over freq (seq len 16) ----------------
__global__ __launch_bounds__(256) void k_intra_lstm(
    const float* __restrict__ hc,
    const float* __restrict__ wiTf, const float* __restrict__ whTf,
    const float* __restrict__ bihf, const float* __restrict__ bhhf,
    const float* __restrict__ wiTr, const float* __restrict__ whTr,
    const float* __restrict__ bihr, const float* __restrict__ bhhr,
    float* __restrict__ yf, float* __restrict__ yr) {
  __shared__ float xt[1024];    // [8][128]
  __shared__ float hsh[2048];   // [8][256]
  __shared__ float csh[2048];
  __shared__ float gbuf[8192];  // [8][1024]
  int tid = threadIdx.x;
  int grp = blockIdx.x & 255, dir = blockIdx.x >> 8;
  int n0 = grp * 8;
  const float4* wi4 = (const float4*)(dir ? wiTr : wiTf);
  const float4* wh4 = (const float4*)(dir ? whTr : whTf);
  const float* bi = dir ? bihr : bihf;
  const float* bh = dir ? bhhr : bhhf;
  float* yo = dir ? yr : yf;
  float bias[4];
  #pragma unroll
  for (int j = 0; j < 4; ++j) bias[j] = bi[4 * tid + j] + bh[4 * tid + j];
  for (int e = tid; e < 2048; e += 256) { hsh[e] = 0.f; csh[e] = 0.f; }
  for (int t = 0; t < 16; ++t) {
    int tt = dir ? 15 - t : t;
    for (int e = tid; e < 1024; e += 256)
      xt[e] = hc[((size_t)(n0 + (e >> 7)) * 16 + tt) * 128 + (e & 127)];
    __syncthreads();
    float acc[4][8];
    #pragma unroll
    for (int j = 0; j < 4; ++j)
      #pragma unroll
      for (int s = 0; s < 8; ++s) acc[j][s] = bias[j];
    for (int k = 0; k < 128; ++k) {
      float4 w = wi4[k * 256 + tid];
      #pragma unroll
      for (int s = 0; s < 8; ++s) {
        float xv = xt[s * 128 + k];
        acc[0][s] += w.x * xv; acc[1][s] += w.y * xv;
        acc[2][s] += w.z * xv; acc[3][s] += w.w * xv;
      }
    }
    for (int k = 0; k < 256; ++k) {
      float4 w = wh4[k * 256 + tid];
      #pragma unroll
      for (int s = 0; s < 8; ++s) {
        float hv = hsh[s * 256 + k];
        acc[0][s] += w.x * hv; acc[1][s] += w.y * hv;
        acc[2][s] += w.z * hv; acc[3][s] += w.w * hv;
      }
    }
    #pragma unroll
    for (int j = 0; j < 4; ++j)
      #pragma unroll
      for (int s = 0; s < 8; ++s)
        gbuf[s * 1024 + 4 * tid + j] = acc[j][s];
    __syncthreads();
    #pragma unroll
    for (int s = 0; s < 8; ++s) {
      float iv = gbuf[s * 1024 + tid];
      float fv = gbuf[s * 1024 + 256 + tid];
      float gv = gbuf[s * 1024 + 512 + tid];
      float ov = gbuf[s * 1024 + 768 + tid];
      float cn = sigf(fv) * csh[s * 256 + tid] + sigf(iv) * tanh_(gv);
      float hn = sigf(ov) * tanh_(cn);
      csh[s * 256 + tid] = cn;
      hsh[s * 256 + tid] = hn;
      yo[((size_t)(n0 + s) * 16 + tt) * 256 + tid] = hn;   // stored at ORIGINAL pos
    }
    __syncthreads();
  }
}

// ---------------- deconv(k=s=4) + bias + pad + residual ----------------
__global__ __launch_bounds__(256) void k_deconv(
    const float* __restrict__ yf, const float* __restrict__ yr,
    const float* __restrict__ dw, const float* __restrict__ db,
    const float* __restrict__ x32, float* __restrict__ intra) {
  __shared__ float hbi[8192];   // [16][512]
  int n = blockIdx.x, tid = threadIdx.x;
  for (int e = tid; e < 8192; e += 256) {
    int i = e >> 9, d = e & 511;
    hbi[e] = d < 256 ? yf[((size_t)n * 16 + i) * 256 + d]
                     : yr[((size_t)n * 16 + i) * 256 + d - 256];
  }
  __syncthreads();
  int op0 = tid, op1 = tid + 256;   // op = o*4 + m
  float acc0[16], acc1[16];
  #pragma unroll
  for (int i = 0; i < 16; ++i) { acc0[i] = 0.f; acc1[i] = 0.f; }
  for (int d = 0; d < 512; d += 2) {
    float w00 = dw[(size_t)d * 512 + op0];
    float w01 = dw[(size_t)d * 512 + op1];
    float w10 = dw[(size_t)(d + 1) * 512 + op0];
    float w11 = dw[(size_t)(d + 1) * 512 + op1];
    #pragma unroll
    for (int i = 0; i < 16; ++i) {
      float2 hv = *(const float2*)&hbi[i * 512 + d];
      acc0[i] += hv.x * w00 + hv.y * w10;
      acc1[i] += hv.x * w01 + hv.y * w11;
    }
  }
  int o0 = op0 >> 2, m0 = op0 & 3, o1 = op1 >> 2, m1 = op1 & 3;
  float db0 = db[o0], db1 = db[o1];
  #pragma unroll
  for (int i = 0; i < 16; ++i) {
    size_t i0 = ((size_t)n * 65 + i * 4 + m0) * 128 + o0;
    size_t i1 = ((size_t)n * 65 + i * 4 + m1) * 128 + o1;
    intra[i0] = acc0[i] + db0 + x32[i0];
    intra[i1] = acc1[i] + db1 + x32[i1];
  }
  if (tid < 128) {   // padded freq row 64: zeros + bias + residual
    size_t ip = ((size_t)n * 65 + 64) * 128 + tid;
    intra[ip] = db[tid] + x32[ip];
  }
}

// ---------------- LN over C + transpose to [B*NF][T][C] ----------------
__global__ __launch_bounds__(256) void k_ln1(
    const float* __restrict__ intra, const float* __restrict__ g1,
    const float* __restrict__ b1, float* __restrict__ out) {
  __shared__ float rs[4], rq[4];
  int n = blockIdx.x, tid = threadIdx.x;
  int gr = tid >> 7, o = tid & 127, wid = tid >> 6;
  int b = n >> 9, t = n & 511;
  float gv = g1[o], bv = b1[o];
  for (int f0 = 0; f0 < 65; f0 += 2) {
    int f = f0 + gr;
    bool ok = f < 65;
    float v = 0.f;
    if (ok) v = intra[((size_t)n * 65 + f) * 128 + o];
    float s = v, q = v * v;
    wavered2(s, q);
    if ((tid & 63) == 0) { rs[wid] = s; rq[wid] = q; }
    __syncthreads();
    if (ok) {
      float S = rs[2 * gr] + rs[2 * gr + 1], Q = rq[2 * gr] + rq[2 * gr + 1];
      float mu = S / 128.f;
      float rinv = rsqrtf(fmaxf(Q / 128.f - mu * mu, 0.f) + 1e-5f);
      out[((size_t)(b * 65 + f) * 512 + t) * 128 + o] = (v - mu) * rinv * gv + bv;
    }
    __syncthreads();
  }
}

// ---------------- inter causal LSTM over time + fused Linear + residual ----
// 130 blocks x 1024 threads, TWO sequences per block, 1 block/CU (no spills).
// 4-way K-split: group g (256 threads) covers x-k [32g,32g+32) and
// h-k [64g,64g+64) for BOTH sequences; LDS reduce; bf16 weights k-major.
__global__ __launch_bounds__(1024, 4) void k_inter_lstm(
    const float* __restrict__ ln1y,
    const u16* __restrict__ wiTb, const u16* __restrict__ whTb,
    const float* __restrict__ bih, const float* __restrict__ bhh,
    const float* __restrict__ lw, const float* __restrict__ lb,
    const float* __restrict__ h0a, const float* __restrict__ c0a,
    const float* __restrict__ intra, float* __restrict__ inter) {
  __shared__ float xt[256];        // [2][128]
  __shared__ float hsh[512];       // [2][256]
  __shared__ float csh[512];
  __shared__ float pb[4][2][1024]; // gate partials (32 KB); pb[0] reused for lin
  int tid = threadIdx.x;
  int n0 = blockIdx.x * 2;
  int g = tid >> 8, l = tid & 255;
  if (tid < 512) {
    hsh[tid] = h0a[(size_t)n0 * 256 + tid];
    csh[tid] = c0a[(size_t)n0 * 256 + tid];
  }
  // P3 mapping (tid<512): seq s3 = tid>>8, h-elem j3 = tid&255
  int s3 = tid >> 8, j3 = tid & 255;
  float bi_i = 0.f, bi_f = 0.f, bi_g = 0.f, bi_o = 0.f;
  if (tid < 512) {
    bi_i = bih[j3] + bhh[j3];
    bi_f = bih[256 + j3] + bhh[256 + j3];
    bi_g = bih[512 + j3] + bhh[512 + j3];
    bi_o = bih[768 + j3] + bhh[768 + j3];
  }
  // P1/P5 mapping (tid<256): seq s5 = tid>>7, channel c5 = tid&127
  int s5 = tid >> 7, c5 = tid & 127;
  int n_l = n0 + s5;
  int b_l = n_l / 65, f_l = n_l - b_l * 65;
  float linb = (tid < 256) ? lb[c5] : 0.f;
  // P4 mapping (all 1024): seq s4 = tid>>9, channel c4 = (tid>>2)&127, part = tid&3
  int s4 = tid >> 9, c4 = (tid >> 2) & 127, part = tid & 3;
  const float4* lr4 = (const float4*)(lw + (size_t)c4 * 256 + part * 64);
  // P2 weight pointers (k-major rows of 1024 gates; thread owns cols 4l..4l+3)
  const u16* wip = wiTb + (size_t)(g * 32) * 1024 + 4 * l;
  const u16* whp = whTb + (size_t)(g * 64) * 1024 + 4 * l;
  int kw0 = g * 32, kh0 = g * 64;
  __syncthreads();
  for (int t = 0; t < 512; ++t) {
    // P1: stage x_t (both seqs), prefetch residual
    float resid = 0.f;
    size_t oi = 0;
    if (tid < 256) {
      xt[tid] = ln1y[(size_t)n_l * 65536 + (size_t)t * 128 + c5];
      oi = ((size_t)(b_l * 512 + t) * 65 + f_l) * 128 + c5;
      resid = intra[oi];
    }
    __syncthreads();
    // P2: partial gate dot products over this group's k-slice, both seqs
    float a00 = 0.f, a01 = 0.f, a02 = 0.f, a03 = 0.f;
    float a10 = 0.f, a11 = 0.f, a12 = 0.f, a13 = 0.f;
    #pragma unroll 8
    for (int k = 0; k < 32; ++k) {
      ushort4 u = *(const ushort4*)(wip + (size_t)k * 1024);
      float w0 = b2f(u.x), w1 = b2f(u.y), w2 = b2f(u.z), w3 = b2f(u.w);
      float x0 = xt[kw0 + k], x1 = xt[128 + kw0 + k];
      a00 += w0 * x0; a01 += w1 * x0; a02 += w2 * x0; a03 += w3 * x0;
      a10 += w0 * x1; a11 += w1 * x1; a12 += w2 * x1; a13 += w3 * x1;
    }
    #pragma unroll 8
    for (int k = 0; k < 64; ++k) {
      ushort4 u = *(const ushort4*)(whp + (size_t)k * 1024);
      float w0 = b2f(u.x), w1 = b2f(u.y), w2 = b2f(u.z), w3 = b2f(u.w);
      float h0v = hsh[kh0 + k], h1v = hsh[256 + kh0 + k];
      a00 += w0 * h0v; a01 += w1 * h0v; a02 += w2 * h0v; a03 += w3 * h0v;
      a10 += w0 * h1v; a11 += w1 * h1v; a12 += w2 * h1v; a13 += w3 * h1v;
    }
    pb[g][0][4 * l]     = a00; pb[g][0][4 * l + 1] = a01;
    pb[g][0][4 * l + 2] = a02; pb[g][0][4 * l + 3] = a03;
    pb[g][1][4 * l]     = a10; pb[g][1][4 * l + 1] = a11;
    pb[g][1][4 * l + 2] = a12; pb[g][1][4 * l + 3] = a13;
    __syncthreads();
    // P3: reduce partials, gate nonlinearities, state update (both seqs)
    if (tid < 512) {
      float iv = bi_i + pb[0][s3][j3] + pb[1][s3][j3] + pb[2][s3][j3] + pb[3][s3][j3];
      float fv = bi_f + pb[0][s3][256 + j3] + pb[1][s3][256 + j3]
                      + pb[2][s3][256 + j3] + pb[3][s3][256 + j3];
      float gv = bi_g + pb[0][s3][512 + j3] + pb[1][s3][512 + j3]
                      + pb[2][s3][512 + j3] + pb[3][s3][512 + j3];
      float ov = bi_o + pb[0][s3][768 + j3] + pb[1][s3][768 + j3]
                      + pb[2][s3][768 + j3] + pb[3][s3][768 + j3];
      float cn = sigf(fv) * csh[s3 * 256 + j3] + sigf(iv) * tanh_(gv);
      float hn = sigf(ov) * tanh_(cn);
      csh[s3 * 256 + j3] = cn;
      hsh[s3 * 256 + j3] = hn;
    }
    __syncthreads();
    // P4: fused Linear partials (all 1024 threads; 64 k each)
    {
      const float* hk = hsh + s4 * 256 + part * 64;
      float acc = 0.f;
      #pragma unroll 4
      for (int qq = 0; qq < 16; ++qq) {
        float4 w = lr4[qq];
        acc += w.x * hk[4 * qq] + w.y * hk[4 * qq + 1]
             + w.z * hk[4 * qq + 2] + w.w * hk[4 * qq + 3];
      }
      pb[0][s4][4 * c4 + part] = acc;   // pb consumed in P3; safe to reuse
    }
    __syncthreads();
    // P5: combine lin partials + residual store
    if (tid < 256) {
      float acc = linb + resid;
      acc += pb[0][s5][4 * c5] + pb[0][s5][4 * c5 + 1]
           + pb[0][s5][4 * c5 + 2] + pb[0][s5][4 * c5 + 3];
      inter[oi] = acc;
    }
    // next-iter P1 barrier orders pb/xt overwrites after P5
  }
}

// ---------------- Q/K/V projections + PReLU (pre-LN) ----------------
__global__ __launch_bounds__(256) void k_qkv(
    const float* __restrict__ inter,
    const float* __restrict__ qw, const float* __restrict__ qb, const float* __restrict__ qa,
    const float* __restrict__ kw, const float* __restrict__ kb, const float* __restrict__ ka,
    const float* __restrict__ vw, const float* __restrict__ vb, const float* __restrict__ va,
    float* __restrict__ Qh, float* __restrict__ Kh, float* __restrict__ Vh) {
  __shared__ float xsl[8320];
  int n = blockIdx.x, tid = threadIdx.x;
  int b = n >> 9, t = n & 511;
  for (int e = tid; e < 8320; e += 256) xsl[e] = inter[(size_t)n * 8320 + e];
  __syncthreads();
  if (tid >= 192) return;
  const float* wrow; float bias, a; float* dst; int dsz;
  if (tid < 32) {
    wrow = qw + (size_t)tid * 128; bias = qb[tid]; a = qa[0];
    dst = Qh + ((size_t)(b * 4 + (tid >> 3)) * 512 + t) * 520 + (tid & 7); dsz = 8;
  } else if (tid < 64) {
    int d = tid - 32;
    wrow = kw + (size_t)d * 128; bias = kb[d]; a = ka[0];
    dst = Kh + ((size_t)(b * 4 + (d >> 3)) * 512 + t) * 520 + (d & 7); dsz = 8;
  } else {
    int d = tid - 64;
    wrow = vw + (size_t)d * 128; bias = vb[d]; a = va[0];
    dst = Vh + ((size_t)(b * 4 + (d >> 5)) * 512 + t) * 2080 + (d & 31); dsz = 32;
  }
  const float4* w4 = (const float4*)wrow;
  for (int f = 0; f < 65; ++f) {
    float acc = bias;
    const float4* xr = (const float4*)&xsl[f * 128];
    #pragma unroll
    for (int kk = 0; kk < 32; ++kk) {
      float4 w = w4[kk], xv = xr[kk];
      acc += w.x * xv.x + w.y * xv.y + w.z * xv.z + w.w * xv.w;
    }
    acc = acc >= 0.f ? acc : a * acc;
    dst[(size_t)f * dsz] = acc;
  }
}

// ---------------- LN over last dim (in-place) ----------------
__global__ __launch_bounds__(256) void k_lnrow(
    float* __restrict__ buf, int len,
    const float* __restrict__ g, const float* __restrict__ b) {
  __shared__ float rs[4], rq[4];
  int row = blockIdx.x, tid = threadIdx.x;
  float* p = buf + (size_t)row * len;
  float s = 0.f, q = 0.f;
  for (int e = tid; e < len; e += 256) { float v = p[e]; s += v; q += v * v; }
  wavered2(s, q);
  if ((tid & 63) == 0) { rs[tid >> 6] = s; rq[tid >> 6] = q; }
  __syncthreads();
  float S = rs[0] + rs[1] + rs[2] + rs[3];
  float Q = rq[0] + rq[1] + rq[2] + rq[3];
  float mu = S / len;
  float rinv = rsqrtf(fmaxf(Q / len - mu * mu, 0.f) + 1e-5f);
  for (int e = tid; e < len; e += 256) {
    float v = p[e];
    p[e] = (v - mu) * rinv * g[e] + b[e];
  }
}

// ---------------- windowed causal attention (100 keys) ----------------
__global__ __launch_bounds__(256) void k_attn(
    const float* __restrict__ Qh, const float* __restrict__ Kh,
    const float* __restrict__ Vh, const float* __restrict__ Kbuf,
    const float* __restrict__ Vbuf, float* __restrict__ av) {
  __shared__ float qrow[520], sc[100], red[2];
  int bid = blockIdx.x, tid = threadIdx.x;
  int bh = bid >> 9, t = bid & 511;
  for (int e = tid; e < 520; e += 256)
    qrow[e] = Qh[((size_t)bh * 512 + t) * 520 + e];
  __syncthreads();
  if (tid < 100) {
    int s = t + tid;
    float acc = 0.f;
    if (s < 99) {
      const float* kr = Kbuf + ((size_t)bh * 99 + s) * 520;
      for (int e = 0; e < 520; ++e) acc += qrow[e] * kr[e];
    } else {
      const float* kr = Kh + ((size_t)bh * 512 + (s - 99)) * 520;
      for (int e = 0; e < 520; ++e) acc += qrow[e] * kr[e];
    }
    sc[tid] = acc * 0.04385290096535147f;   // 1/sqrt(520)
  }
  __syncthreads();
  if (tid == 0) {
    float m = sc[0];
    for (int k = 1; k < 100; ++k) m = fmaxf(m, sc[k]);
    red[0] = m;
  }
  __syncthreads();
  if (tid < 100) sc[tid] = __expf(sc[tid] - red[0]);
  __syncthreads();
  if (tid == 0) {
    float s = 0.f;
    for (int k = 0; k < 100; ++k) s += sc[k];
    red[1] = 1.f / s;
  }
  __syncthreads();
  float rscale = red[1];
  int b = bh >> 2, nh = bh & 3;
  int kb = t < 99 ? 99 - t : 0;
  for (int o = tid; o < 2080; o += 256) {
    float acc = 0.f;
    for (int k = 0; k < kb; ++k)
      acc += sc[k] * Vbuf[((size_t)bh * 99 + t + k) * 2080 + o];
    for (int k = kb; k < 100; ++k)
      acc += sc[k] * Vh[((size_t)bh * 512 + (t + k - 99)) * 2080 + o];
    int f = o >> 5, vd = o & 31;
    av[((size_t)(b * 512 + t) * 65 + f) * 128 + nh * 32 + vd] = acc * rscale;
  }
}

// ---------------- P projection + PReLU ----------------
__global__ __launch_bounds__(256) void k_pproj(
    const float* __restrict__ av, const float* __restrict__ pw,
    const float* __restrict__ pb, const float* __restrict__ pa,
    float* __restrict__ ph) {
  __shared__ float avs[8320];
  int n = blockIdx.x, tid = threadIdx.x;
  for (int e = tid; e < 8320; e += 256) avs[e] = av[(size_t)n * 8320 + e];
  __syncthreads();
  int o = tid & 127, g = tid >> 7;
  float a = pa[0], bias = pb[o];
  const float4* w4 = (const float4*)(pw + (size_t)o * 128);
  for (int f = g; f < 65; f += 2) {
    float acc = bias;
    const float4* xr = (const float4*)&avs[f * 128];
    #pragma unroll
    for (int kk = 0; kk < 32; ++kk) {
      float4 w = w4[kk], xv = xr[kk];
      acc += w.x * xv.x + w.y * xv.y + w.z * xv.z + w.w * xv.w;
    }
    acc = acc >= 0.f ? acc : a * acc;
    ph[(size_t)n * 8320 + f * 128 + o] = acc;
  }
}

// ---------------- final LN(8320) + residual -> fp32 out ----------------
__global__ __launch_bounds__(256) void k_lnfinal(
    const float* __restrict__ ph, const float* __restrict__ plg,
    const float* __restrict__ plb, const float* __restrict__ inter,
    float* __restrict__ out) {
  __shared__ float rs[4], rq[4];
  int n = blockIdx.x, tid = threadIdx.x;
  const float* p = ph + (size_t)n * 8320;
  float s = 0.f, q = 0.f;
  for (int e = tid; e < 8320; e += 256) { float v = p[e]; s += v; q += v * v; }
  wavered2(s, q);
  if ((tid & 63) == 0) { rs[tid >> 6] = s; rq[tid >> 6] = q; }
  __syncthreads();
  float S = rs[0] + rs[1] + rs[2] + rs[3];
  float Q = rq[0] + rq[1] + rq[2] + rq[3];
  float mu = S / 8320.f;
  float rinv = rsqrtf(fmaxf(Q / 8320.f - mu * mu, 0.f) + 1e-5f);
  for (int e = tid; e < 8320; e += 256) {
    out[(size_t)n * 8320 + e] =
        (p[e] - mu) * rinv * plg[e] + plb[e] + inter[(size_t)n * 8320 + e];
  }
}

extern "C" void kernel_launch(void* const* d_in, const int* in_sizes, int n_in,
                              void* d_out, int out_size, void* d_ws, size_t ws_size,
                              hipStream_t stream) {
  const float* x       = (const float*)d_in[0];
  const float* conv_w  = (const float*)d_in[1];
  const float* conv_b  = (const float*)d_in[2];
  const float* conv_a  = (const float*)d_in[3];
  const float* ln0_g   = (const float*)d_in[4];
  const float* ln0_b   = (const float*)d_in[5];
  const float* iwih_f  = (const float*)d_in[6];
  const float* iwhh_f  = (const float*)d_in[7];
  const float* ibih_f  = (const float*)d_in[8];
  const float* ibhh_f  = (const float*)d_in[9];
  const float* iwih_r  = (const float*)d_in[10];
  const float* iwhh_r  = (const float*)d_in[11];
  const float* ibih_r  = (const float*)d_in[12];
  const float* ibhh_r  = (const float*)d_in[13];
  const float* deconv_w= (const float*)d_in[14];
  const float* deconv_b= (const float*)d_in[15];
  const float* ln1_g   = (const float*)d_in[16];
  const float* ln1_b   = (const float*)d_in[17];
  const float* wih     = (const float*)d_in[18];
  const float* whh     = (const float*)d_in[19];
  const float* bih     = (const float*)d_in[20];
  const float* bhh     = (const float*)d_in[21];
  const float* lin_w   = (const float*)d_in[22];
  const float* lin_b   = (const float*)d_in[23];
  const float* q_w     = (const float*)d_in[24];
  const float* q_b     = (const float*)d_in[25];
  const float* q_a     = (const float*)d_in[26];
  const float* q_lg    = (const float*)d_in[27];
  const float* q_lb    = (const float*)d_in[28];
  const float* k_w     = (const float*)d_in[29];
  const float* k_b     = (const float*)d_in[30];
  const float* k_a     = (const float*)d_in[31];
  const float* k_lg    = (const float*)d_in[32];
  const float* k_lb    = (const float*)d_in[33];
  const float* v_w     = (const float*)d_in[34];
  const float* v_b     = (const float*)d_in[35];
  const float* v_a     = (const float*)d_in[36];
  const float* v_lg    = (const float*)d_in[37];
  const float* v_lb    = (const float*)d_in[38];
  const float* p_w     = (const float*)d_in[39];
  const float* p_b     = (const float*)d_in[40];
  const float* p_a     = (const float*)d_in[41];
  const float* p_lg    = (const float*)d_in[42];
  const float* p_lb    = (const float*)d_in[43];
  const float* K_buf   = (const float*)d_in[44];
  const float* V_buf   = (const float*)d_in[45];
  const float* h0v     = (const float*)d_in[46];
  const float* c0v     = (const float*)d_in[47];

  char* ws = (char*)d_ws;
  float* hc    = (float*)(ws + OFF_A);
  float* yfb   = (float*)(ws + OFF_A + 16777216ULL);
  float* yrb   = (float*)(ws + OFF_DE);
  float* ln1y  = (float*)(ws + OFF_A);
  float* Vh    = (float*)(ws + OFF_A);
  float* phb   = (float*)(ws + OFF_A);
  float* intra = (float*)(ws + OFF_B);
  float* avb   = (float*)(ws + OFF_B);
  float* inter = (float*)(ws + OFF_C);
  float* Qh    = (float*)(ws + OFF_DE);
  float* Kh    = (float*)(ws + OFF_DE + 17039360ULL);
  float* wT    = (float*)(ws + OFF_WT);
  float* wiTf = wT + 0;        // 131072 floats
  float* whTf = wT + 131072;   // 262144
  float* wiTr = wT + 393216;   // 131072
  float* whTr = wT + 524288;   // 262144 -> ends at 786432 floats (3 MB)
  u16* wiTb = (u16*)(wT + 786432);      // 131072 u16 (256 KB)
  u16* whTb = wiTb + 131072;            // 262144 u16 (512 KB)

  k_transpose_ff<<<512, 256, 0, stream>>>(iwih_f, wiTf, 1024, 128);
  k_transpose_ff<<<1024, 256, 0, stream>>>(iwhh_f, whTf, 1024, 256);
  k_transpose_ff<<<512, 256, 0, stream>>>(iwih_r, wiTr, 1024, 128);
  k_transpose_ff<<<1024, 256, 0, stream>>>(iwhh_r, whTr, 1024, 256);
  k_transpose_fb<<<512, 256, 0, stream>>>(wih, wiTb, 1024, 128);
  k_transpose_fb<<<1024, 256, 0, stream>>>(whh, whTb, 1024, 256);

  k_conv_ln0<<<2048, 256, 0, stream>>>(x, conv_w, conv_b, conv_a, ln0_g, ln0_b, hc);
  k_intra_lstm<<<512, 256, 0, stream>>>(hc, wiTf, whTf, ibih_f, ibhh_f,
                                        wiTr, whTr, ibih_r, ibhh_r, yfb, yrb);
  k_deconv<<<2048, 256, 0, stream>>>(yfb, yrb, deconv_w, deconv_b, x, intra);
  k_ln1<<<2048, 256, 0, stream>>>(intra, ln1_g, ln1_b, ln1y);
  k_inter_lstm<<<130, 1024, 0, stream>>>(ln1y, wiTb, whTb, bih, bhh,
                                         lin_w, lin_b, h0v, c0v, intra, inter);
  k_qkv<<<2048, 256, 0, stream>>>(inter, q_w, q_b, q_a, k_w, k_b, k_a,
                                  v_w, v_b, v_a, Qh, Kh, Vh);
  k_lnrow<<<8192, 256, 0, stream>>>(Qh, 520, q_lg, q_lb);
  k_lnrow<<<8192, 256, 0, stream>>>(Kh, 520, k_lg, k_lb);
  k_lnrow<<<8192, 256, 0, stream>>>(Vh, 2080, v_lg, v_lb);
  k_attn<<<8192, 256, 0, stream>>>(Qh, Kh, Vh, K_buf, V_buf, avb);
  k_pproj<<<2048, 256, 0, stream>>>(avb, p_w, p_b, p_a, phb);
  k_lnfinal<<<2048, 256, 0, stream>>>(phb, p_lg, p_lb, inter, (float*)d_out);
}

// Round 6
// 6948.230 us; speedup vs baseline: 9.2150x; 1.7839x over previous
//
#include <hip/hip_runtime.h>
#include <hip/hip_bf16.h>

// GridNetBlock round-6. dtypes: ALL FP32 (established R0-R4).
// R5 post-mortem: k_inter_lstm was LDS-pipe bound (~4300 DS insts/CU/step
// ~= 25k cyc; SQ_LDS_BANK_CONFLICT 2e8 from P4's part*64 stride). R6 changes
// (k_inter_lstm only): 8-way k-split with 8 gate-cols/thread (1 dwordx4
// weight load + 1 ds_read_b64 per k-row -> 16 FMA), [k][2] paired LDS layout
// for x/h (one b64 read serves both seqs), P4 rewritten with rotated k-chunks
// (bank-conflict-free), lin_w cast to bf16, nontemporal stream hints.
// B=4 T=512 NF=65 C=128 NH=4 E=8 H=256 DOWN=4 L=100 VD=32.
//
// ws layout (bytes):
//  A [0,68.2M):        hc[16.8M]+yf[33.5M]  ->  ln1y -> Vh -> ph
//  B [68.2M,136.3M):   intra -> av
//  C [136.3M,204.5M):  inter
//  DE[204.5M,238.6M):  yr[33.5M] -> Qh[17M]+Kh[17M]
//  WT[238.6M,242.6M):  fp32 transposed intra weights + bf16 inter weights

typedef unsigned short u16;
typedef unsigned int u32;

#define OFF_A    0ULL
#define OFF_B    68157440ULL
#define OFF_C    136314880ULL
#define OFF_DE   204472320ULL
#define OFF_WT   238551040ULL

__device__ __forceinline__ float b2f(u16 u) {
  union { u32 i; float f; } v; v.i = ((u32)u) << 16; return v.f;
}
__device__ __forceinline__ float bflo(u32 u) {
  union { u32 i; float f; } v; v.i = u << 16; return v.f;
}
__device__ __forceinline__ float bfhi(u32 u) {
  union { u32 i; float f; } v; v.i = u & 0xffff0000u; return v.f;
}
__device__ __forceinline__ float sigf(float x) { return 1.f / (1.f + __expf(-x)); }
__device__ __forceinline__ float tanh_(float x) {
  float cx = fminf(15.f, fmaxf(-15.f, x));
  float e = __expf(2.f * cx);
  return (e - 1.f) / (e + 1.f);
}
__device__ __forceinline__ void wavered2(float& s, float& q) {
  #pragma unroll
  for (int o = 32; o > 0; o >>= 1) {
    s += __shfl_down(s, o, 64);
    q += __shfl_down(q, o, 64);
  }
}

// ---------------- transpose fp32 [R][K] -> fp32 [K][R] ----------------
__global__ void k_transpose_ff(const float* __restrict__ src, float* __restrict__ dst,
                               int R, int K) {
  int e = blockIdx.x * 256 + threadIdx.x;
  if (e >= R * K) return;
  int r = e / K, k = e - r * K;
  dst[k * R + r] = src[e];
}

// ---------------- transpose fp32 [R][K] -> bf16 [K][R] ----------------
__global__ void k_transpose_fb(const float* __restrict__ src, u16* __restrict__ dst,
                               int R, int K) {
  int e = blockIdx.x * 256 + threadIdx.x;
  if (e >= R * K) return;
  int r = e / K, k = e - r * K;
  __hip_bfloat16 h = __float2bfloat16(src[e]);
  dst[k * R + r] = *(u16*)&h;
}

// ---------------- cast fp32 -> bf16 (same layout) ----------------
__global__ void k_cast_fb(const float* __restrict__ src, u16* __restrict__ dst, int n) {
  int e = blockIdx.x * 256 + threadIdx.x;
  if (e >= n) return;
  __hip_bfloat16 h = __float2bfloat16(src[e]);
  dst[e] = *(u16*)&h;
}

// ---------------- conv(k=s=4) + bias + PReLU + LN(C) ----------------
__global__ __launch_bounds__(256) void k_conv_ln0(
    const float* __restrict__ x32, const float* __restrict__ cw,
    const float* __restrict__ cb, const float* __restrict__ ca,
    const float* __restrict__ g0, const float* __restrict__ b0,
    float* __restrict__ hc) {
  __shared__ float xs[8192];   // [64 freq][128 c]
  __shared__ float hs[2048];   // [16][128]
  __shared__ float mu_[16], ri_[16];
  int n = blockIdx.x, tid = threadIdx.x;
  const float4* xr = (const float4*)(x32 + (size_t)n * 8320);
  for (int e = tid; e < 2048; e += 256) ((float4*)xs)[e] = xr[e];
  __syncthreads();
  int g = tid >> 7, o = tid & 127;
  float a = ca[0];
  float cbv = cb[o];
  float acc[8];
  #pragma unroll
  for (int j = 0; j < 8; ++j) acc[j] = cbv;
  const float4* cw4 = (const float4*)cw;   // [o][c][4m]
  for (int c = 0; c < 128; ++c) {
    float4 w = cw4[o * 128 + c];
    #pragma unroll
    for (int j = 0; j < 8; ++j) {
      int i = 8 * g + j;
      const float* xi = &xs[i * 512 + c];
      acc[j] += w.x * xi[0] + w.y * xi[128] + w.z * xi[256] + w.w * xi[384];
    }
  }
  #pragma unroll
  for (int j = 0; j < 8; ++j) {
    int i = 8 * g + j;
    float v = acc[j];
    v = v >= 0.f ? v : a * v;
    hs[i * 128 + o] = v;
  }
  __syncthreads();
  if (tid < 16) {
    float s = 0.f, q = 0.f;
    for (int c = 0; c < 128; ++c) { float v = hs[tid * 128 + c]; s += v; q += v * v; }
    float mu = s / 128.f;
    mu_[tid] = mu;
    ri_[tid] = rsqrtf(fmaxf(q / 128.f - mu * mu, 0.f) + 1e-5f);
  }
  __syncthreads();
  float gg = g0[o], bb = b0[o];
  #pragma unroll
  for (int j = 0; j < 8; ++j) {
    int i = 8 * g + j;
    hc[((size_t)n * 16 + i) * 128 + o] = (hs[i * 128 + o] - mu_[i]) * ri_[i] * gg + bb;
  }
}

// ---------------- intra BiLSTM over freq (seq len 16) ----------------
__global__ __launch_bounds__(256) void k_intra_lstm(
    const float* __restrict__ hc,
    const float* __restrict__ wiTf, const float* __restrict__ whTf,
    const float* __restrict__ bihf, const float* __restrict__ bhhf,
    const float* __restrict__ wiTr, const float* __restrict__ whTr,
    const float* __restrict__ bihr, const float* __restrict__ bhhr,
    float* __restrict__ yf, float* __restrict__ yr) {
  __shared__ float xt[1024];    // [8][128]
  __shared__ float hsh[2048];   // [8][256]
  __shared__ float csh[2048];
  __shared__ float gbuf[8192];  // [8][1024]
  int tid = threadIdx.x;
  int grp = blockIdx.x & 255, dir = blockIdx.x >> 8;
  int n0 = grp * 8;
  const float4* wi4 = (const float4*)(dir ? wiTr : wiTf);
  const float4* wh4 = (const float4*)(dir ? whTr : whTf);
  const float* bi = dir ? bihr : bihf;
  const float* bh = dir ? bhhr : bhhf;
  float* yo = dir ? yr : yf;
  float bias[4];
  #pragma unroll
  for (int j = 0; j < 4; ++j) bias[j] = bi[4 * tid + j] + bh[4 * tid + j];
  for (int e = tid; e < 2048; e += 256) { hsh[e] = 0.f; csh[e] = 0.f; }
  for (int t = 0; t < 16; ++t) {
    int tt = dir ? 15 - t : t;
    for (int e = tid; e < 1024; e += 256)
      xt[e] = hc[((size_t)(n0 + (e >> 7)) * 16 + tt) * 128 + (e & 127)];
    __syncthreads();
    float acc[4][8];
    #pragma unroll
    for (int j = 0; j < 4; ++j)
      #pragma unroll
      for (int s = 0; s < 8; ++s) acc[j][s] = bias[j];
    for (int k = 0; k < 128; ++k) {
      float4 w = wi4[k * 256 + tid];
      #pragma unroll
      for (int s = 0; s < 8; ++s) {
        float xv = xt[s * 128 + k];
        acc[0][s] += w.x * xv; acc[1][s] += w.y * xv;
        acc[2][s] += w.z * xv; acc[3][s] += w.w * xv;
      }
    }
    for (int k = 0; k < 256; ++k) {
      float4 w = wh4[k * 256 + tid];
      #pragma unroll
      for (int s = 0; s < 8; ++s) {
        float hv = hsh[s * 256 + k];
        acc[0][s] += w.x * hv; acc[1][s] += w.y * hv;
        acc[2][s] += w.z * hv; acc[3][s] += w.w * hv;
      }
    }
    #pragma unroll
    for (int j = 0; j < 4; ++j)
      #pragma unroll
      for (int s = 0; s < 8; ++s)
        gbuf[s * 1024 + 4 * tid + j] = acc[j][s];
    __syncthreads();
    #pragma unroll
    for (int s = 0; s < 8; ++s) {
      float iv = gbuf[s * 1024 + tid];
      float fv = gbuf[s * 1024 + 256 + tid];
      float gv = gbuf[s * 1024 + 512 + tid];
      float ov = gbuf[s * 1024 + 768 + tid];
      float cn = sigf(fv) * csh[s * 256 + tid] + sigf(iv) * tanh_(gv);
      float hn = sigf(ov) * tanh_(cn);
      csh[s * 256 + tid] = cn;
      hsh[s * 256 + tid] = hn;
      yo[((size_t)(n0 + s) * 16 + tt) * 256 + tid] = hn;   // stored at ORIGINAL pos
    }
    __syncthreads();
  }
}

// ---------------- deconv(k=s=4) + bias + pad + residual ----------------
__global__ __launch_bounds__(256) void k_deconv(
    const float* __restrict__ yf, const float* __restrict__ yr,
    const float* __restrict__ dw, const float* __restrict__ db,
    const float* __restrict__ x32, float* __restrict__ intra) {
  __shared__ float hbi[8192];   // [16][512]
  int n = blockIdx.x, tid = threadIdx.x;
  for (int e = tid; e < 8192; e += 256) {
    int i = e >> 9, d = e & 511;
    hbi[e] = d < 256 ? yf[((size_t)n * 16 + i) * 256 + d]
                     : yr[((size_t)n * 16 + i) * 256 + d - 256];
  }
  __syncthreads();
  int op0 = tid, op1 = tid + 256;   // op = o*4 + m
  float acc0[16], acc1[16];
  #pragma unroll
  for (int i = 0; i < 16; ++i) { acc0[i] = 0.f; acc1[i] = 0.f; }
  for (int d = 0; d < 512; d += 2) {
    float w00 = dw[(size_t)d * 512 + op0];
    float w01 = dw[(size_t)d * 512 + op1];
    float w10 = dw[(size_t)(d + 1) * 512 + op0];
    float w11 = dw[(size_t)(d + 1) * 512 + op1];
    #pragma unroll
    for (int i = 0; i < 16; ++i) {
      float2 hv = *(const float2*)&hbi[i * 512 + d];
      acc0[i] += hv.x * w00 + hv.y * w10;
      acc1[i] += hv.x * w01 + hv.y * w11;
    }
  }
  int o0 = op0 >> 2, m0 = op0 & 3, o1 = op1 >> 2, m1 = op1 & 3;
  float db0 = db[o0], db1 = db[o1];
  #pragma unroll
  for (int i = 0; i < 16; ++i) {
    size_t i0 = ((size_t)n * 65 + i * 4 + m0) * 128 + o0;
    size_t i1 = ((size_t)n * 65 + i * 4 + m1) * 128 + o1;
    intra[i0] = acc0[i] + db0 + x32[i0];
    intra[i1] = acc1[i] + db1 + x32[i1];
  }
  if (tid < 128) {   // padded freq row 64: zeros + bias + residual
    size_t ip = ((size_t)n * 65 + 64) * 128 + tid;
    intra[ip] = db[tid] + x32[ip];
  }
}

// ---------------- LN over C + transpose to [B*NF][T][C] ----------------
__global__ __launch_bounds__(256) void k_ln1(
    const float* __restrict__ intra, const float* __restrict__ g1,
    const float* __restrict__ b1, float* __restrict__ out) {
  __shared__ float rs[4], rq[4];
  int n = blockIdx.x, tid = threadIdx.x;
  int gr = tid >> 7, o = tid & 127, wid = tid >> 6;
  int b = n >> 9, t = n & 511;
  float gv = g1[o], bv = b1[o];
  for (int f0 = 0; f0 < 65; f0 += 2) {
    int f = f0 + gr;
    bool ok = f < 65;
    float v = 0.f;
    if (ok) v = intra[((size_t)n * 65 + f) * 128 + o];
    float s = v, q = v * v;
    wavered2(s, q);
    if ((tid & 63) == 0) { rs[wid] = s; rq[wid] = q; }
    __syncthreads();
    if (ok) {
      float S = rs[2 * gr] + rs[2 * gr + 1], Q = rq[2 * gr] + rq[2 * gr + 1];
      float mu = S / 128.f;
      float rinv = rsqrtf(fmaxf(Q / 128.f - mu * mu, 0.f) + 1e-5f);
      out[((size_t)(b * 65 + f) * 512 + t) * 128 + o] = (v - mu) * rinv * gv + bv;
    }
    __syncthreads();
  }
}

// ---------------- inter causal LSTM over time + fused Linear + residual ----
// 130 blocks x 1024 threads, 2 seqs/block.
// 8-way k-split: group g (128 threads) covers x-k [16g,16g+16) and
// h-k [32g,32g+32); thread owns 8 consecutive gate cols -> one dwordx4
// weight load + one ds_read_b64 (both seqs) per k-row -> 16 FMA.
__global__ __launch_bounds__(1024, 4) void k_inter_lstm(
    const float* __restrict__ ln1y,
    const u16* __restrict__ wiTb, const u16* __restrict__ whTb,
    const float* __restrict__ bih, const float* __restrict__ bhh,
    const u16* __restrict__ lwb, const float* __restrict__ lb,
    const float* __restrict__ h0a, const float* __restrict__ c0a,
    const float* __restrict__ intra, float* __restrict__ inter) {
  __shared__ float xt2[128][2];     // [k][seq]
  __shared__ float hs2[256][2];
  __shared__ float cs2[256][2];
  __shared__ float pb[8][2][1024];  // 64 KB; pb[0] reused for lin partials
  int tid = threadIdx.x;
  int n0 = blockIdx.x * 2;
  // init state
  if (tid < 512) {
    int s = tid >> 8, j = tid & 255;
    hs2[j][s] = h0a[(size_t)(n0 + s) * 256 + j];
    cs2[j][s] = c0a[(size_t)(n0 + s) * 256 + j];
  }
  int g = tid >> 7, l = tid & 127;
  // P3 mapping (tid<512)
  int s3 = tid >> 8, j3 = tid & 255;
  float bi_i = 0.f, bi_f = 0.f, bi_g = 0.f, bi_o = 0.f;
  if (tid < 512) {
    bi_i = bih[j3] + bhh[j3];
    bi_f = bih[256 + j3] + bhh[256 + j3];
    bi_g = bih[512 + j3] + bhh[512 + j3];
    bi_o = bih[768 + j3] + bhh[768 + j3];
  }
  // P1/P5 mapping (tid<256)
  int s5 = tid >> 7, c5 = tid & 127;
  int n_l = n0 + s5;
  int b_l = n_l / 65, f_l = n_l - b_l * 65;
  float linb = (tid < 256) ? lb[c5] : 0.f;
  // P4 mapping: c4 = tid>>3 (col), part8 = tid&7 (k-slice of 32)
  int c4 = tid >> 3, part8 = tid & 7;
  const u16* lwp = lwb + (size_t)c4 * 256 + part8 * 32;
  // P2 weight pointers ([k][1024] bf16; thread owns cols l*8..l*8+7)
  const u16* wip = wiTb + (size_t)(g * 16) * 1024 + l * 8;
  const u16* whp = whTb + (size_t)(g * 32) * 1024 + l * 8;
  int kx0 = g * 16, kh0 = g * 32;
  __syncthreads();
  for (int t = 0; t < 512; ++t) {
    // P1: stage x_t (both seqs, paired layout), prefetch residual
    float resid = 0.f;
    size_t oi = 0;
    if (tid < 256) {
      float xv = __builtin_nontemporal_load(
          &ln1y[(size_t)n_l * 65536 + (size_t)t * 128 + c5]);
      xt2[c5][s5] = xv;
      oi = ((size_t)(b_l * 512 + t) * 65 + f_l) * 128 + c5;
      resid = __builtin_nontemporal_load(&intra[oi]);
    }
    __syncthreads();
    // P2: partial gates over this group's k-slice; 8 cols x 2 seqs
    float a[16];
    #pragma unroll
    for (int i = 0; i < 16; ++i) a[i] = 0.f;
    #pragma unroll 4
    for (int k = 0; k < 16; ++k) {
      uint4 u = *(const uint4*)(wip + (size_t)k * 1024);
      float2 xv = *(const float2*)xt2[kx0 + k];
      float w0 = bflo(u.x), w1 = bfhi(u.x), w2 = bflo(u.y), w3 = bfhi(u.y);
      float w4 = bflo(u.z), w5 = bfhi(u.z), w6 = bflo(u.w), w7 = bfhi(u.w);
      a[0] += w0 * xv.x; a[1] += w1 * xv.x; a[2] += w2 * xv.x; a[3] += w3 * xv.x;
      a[4] += w4 * xv.x; a[5] += w5 * xv.x; a[6] += w6 * xv.x; a[7] += w7 * xv.x;
      a[8] += w0 * xv.y; a[9] += w1 * xv.y; a[10] += w2 * xv.y; a[11] += w3 * xv.y;
      a[12] += w4 * xv.y; a[13] += w5 * xv.y; a[14] += w6 * xv.y; a[15] += w7 * xv.y;
    }
    #pragma unroll 4
    for (int k = 0; k < 32; ++k) {
      uint4 u = *(const uint4*)(whp + (size_t)k * 1024);
      float2 hv = *(const float2*)hs2[kh0 + k];
      float w0 = bflo(u.x), w1 = bfhi(u.x), w2 = bflo(u.y), w3 = bfhi(u.y);
      float w4 = bflo(u.z), w5 = bfhi(u.z), w6 = bflo(u.w), w7 = bfhi(u.w);
      a[0] += w0 * hv.x; a[1] += w1 * hv.x; a[2] += w2 * hv.x; a[3] += w3 * hv.x;
      a[4] += w4 * hv.x; a[5] += w5 * hv.x; a[6] += w6 * hv.x; a[7] += w7 * hv.x;
      a[8] += w0 * hv.y; a[9] += w1 * hv.y; a[10] += w2 * hv.y; a[11] += w3 * hv.y;
      a[12] += w4 * hv.y; a[13] += w5 * hv.y; a[14] += w6 * hv.y; a[15] += w7 * hv.y;
    }
    *(float4*)&pb[g][0][l * 8]     = make_float4(a[0], a[1], a[2], a[3]);
    *(float4*)&pb[g][0][l * 8 + 4] = make_float4(a[4], a[5], a[6], a[7]);
    *(float4*)&pb[g][1][l * 8]     = make_float4(a[8], a[9], a[10], a[11]);
    *(float4*)&pb[g][1][l * 8 + 4] = make_float4(a[12], a[13], a[14], a[15]);
    __syncthreads();
    // P3: reduce 8 partials, gate nonlinearities, state update
    if (tid < 512) {
      float iv = bi_i, fv = bi_f, gv = bi_g, ov = bi_o;
      #pragma unroll
      for (int g2 = 0; g2 < 8; ++g2) {
        iv += pb[g2][s3][j3];
        fv += pb[g2][s3][256 + j3];
        gv += pb[g2][s3][512 + j3];
        ov += pb[g2][s3][768 + j3];
      }
      float cn = sigf(fv) * cs2[j3][s3] + sigf(iv) * tanh_(gv);
      float hn = sigf(ov) * tanh_(cn);
      cs2[j3][s3] = cn;
      hs2[j3][s3] = hn;
    }
    __syncthreads();
    // P4: fused Linear partials; rotated chunks -> distinct banks per part
    {
      float p0 = 0.f, p1 = 0.f;
      #pragma unroll
      for (int j = 0; j < 8; ++j) {
        int ch = (j + part8) & 7;
        uint2 u = *(const uint2*)(lwp + ch * 4);
        int k = part8 * 32 + ch * 4;
        float2 h0 = *(const float2*)hs2[k];
        float2 h1 = *(const float2*)hs2[k + 1];
        float2 h2 = *(const float2*)hs2[k + 2];
        float2 h3 = *(const float2*)hs2[k + 3];
        float w0 = bflo(u.x), w1 = bfhi(u.x), w2 = bflo(u.y), w3 = bfhi(u.y);
        p0 += w0 * h0.x + w1 * h1.x + w2 * h2.x + w3 * h3.x;
        p1 += w0 * h0.y + w1 * h1.y + w2 * h2.y + w3 * h3.y;
      }
      pb[0][0][c4 * 8 + part8] = p0;
      pb[0][1][c4 * 8 + part8] = p1;
    }
    __syncthreads();
    // P5: combine lin partials + residual store
    if (tid < 256) {
      const float4* pp = (const float4*)&pb[0][s5][c5 * 8];
      float4 q0 = pp[0], q1 = pp[1];
      float acc = linb + resid + q0.x + q0.y + q0.z + q0.w
                               + q1.x + q1.y + q1.z + q1.w;
      __builtin_nontemporal_store(acc, &inter[oi]);
    }
    // next-iter P1 barrier orders xt2/pb overwrites after P5
  }
}

// ---------------- Q/K/V projections + PReLU (pre-LN) ----------------
__global__ __launch_bounds__(256) void k_qkv(
    const float* __restrict__ inter,
    const float* __restrict__ qw, const float* __restrict__ qb, const float* __restrict__ qa,
    const float* __restrict__ kw, const float* __restrict__ kb, const float* __restrict__ ka,
    const float* __restrict__ vw, const float* __restrict__ vb, const float* __restrict__ va,
    float* __restrict__ Qh, float* __restrict__ Kh, float* __restrict__ Vh) {
  __shared__ float xsl[8320];
  int n = blockIdx.x, tid = threadIdx.x;
  int b = n >> 9, t = n & 511;
  for (int e = tid; e < 8320; e += 256) xsl[e] = inter[(size_t)n * 8320 + e];
  __syncthreads();
  if (tid >= 192) return;
  const float* wrow; float bias, a; float* dst; int dsz;
  if (tid < 32) {
    wrow = qw + (size_t)tid * 128; bias = qb[tid]; a = qa[0];
    dst = Qh + ((size_t)(b * 4 + (tid >> 3)) * 512 + t) * 520 + (tid & 7); dsz = 8;
  } else if (tid < 64) {
    int d = tid - 32;
    wrow = kw + (size_t)d * 128; bias = kb[d]; a = ka[0];
    dst = Kh + ((size_t)(b * 4 + (d >> 3)) * 512 + t) * 520 + (d & 7); dsz = 8;
  } else {
    int d = tid - 64;
    wrow = vw + (size_t)d * 128; bias = vb[d]; a = va[0];
    dst = Vh + ((size_t)(b * 4 + (d >> 5)) * 512 + t) * 2080 + (d & 31); dsz = 32;
  }
  const float4* w4 = (const float4*)wrow;
  for (int f = 0; f < 65; ++f) {
    float acc = bias;
    const float4* xr = (const float4*)&xsl[f * 128];
    #pragma unroll
    for (int kk = 0; kk < 32; ++kk) {
      float4 w = w4[kk], xv = xr[kk];
      acc += w.x * xv.x + w.y * xv.y + w.z * xv.z + w.w * xv.w;
    }
    acc = acc >= 0.f ? acc : a * acc;
    dst[(size_t)f * dsz] = acc;
  }
}

// ---------------- LN over last dim (in-place) ----------------
__global__ __launch_bounds__(256) void k_lnrow(
    float* __restrict__ buf, int len,
    const float* __restrict__ g, const float* __restrict__ b) {
  __shared__ float rs[4], rq[4];
  int row = blockIdx.x, tid = threadIdx.x;
  float* p = buf + (size_t)row * len;
  float s = 0.f, q = 0.f;
  for (int e = tid; e < len; e += 256) { float v = p[e]; s += v; q += v * v; }
  wavered2(s, q);
  if ((tid & 63) == 0) { rs[tid >> 6] = s; rq[tid >> 6] = q; }
  __syncthreads();
  float S = rs[0] + rs[1] + rs[2] + rs[3];
  float Q = rq[0] + rq[1] + rq[2] + rq[3];
  float mu = S / len;
  float rinv = rsqrtf(fmaxf(Q / len - mu * mu, 0.f) + 1e-5f);
  for (int e = tid; e < len; e += 256) {
    float v = p[e];
    p[e] = (v - mu) * rinv * g[e] + b[e];
  }
}

// ---------------- windowed causal attention (100 keys) ----------------
__global__ __launch_bounds__(256) void k_attn(
    const float* __restrict__ Qh, const float* __restrict__ Kh,
    const float* __restrict__ Vh, const float* __restrict__ Kbuf,
    const float* __restrict__ Vbuf, float* __restrict__ av) {
  __shared__ float qrow[520], sc[100], red[2];
  int bid = blockIdx.x, tid = threadIdx.x;
  int bh = bid >> 9, t = bid & 511;
  for (int e = tid; e < 520; e += 256)
    qrow[e] = Qh[((size_t)bh * 512 + t) * 520 + e];
  __syncthreads();
  if (tid < 100) {
    int s = t + tid;
    float acc = 0.f;
    if (s < 99) {
      const float* kr = Kbuf + ((size_t)bh * 99 + s) * 520;
      for (int e = 0; e < 520; ++e) acc += qrow[e] * kr[e];
    } else {
      const float* kr = Kh + ((size_t)bh * 512 + (s - 99)) * 520;
      for (int e = 0; e < 520; ++e) acc += qrow[e] * kr[e];
    }
    sc[tid] = acc * 0.04385290096535147f;   // 1/sqrt(520)
  }
  __syncthreads();
  if (tid == 0) {
    float m = sc[0];
    for (int k = 1; k < 100; ++k) m = fmaxf(m, sc[k]);
    red[0] = m;
  }
  __syncthreads();
  if (tid < 100) sc[tid] = __expf(sc[tid] - red[0]);
  __syncthreads();
  if (tid == 0) {
    float s = 0.f;
    for (int k = 0; k < 100; ++k) s += sc[k];
    red[1] = 1.f / s;
  }
  __syncthreads();
  float rscale = red[1];
  int b = bh >> 2, nh = bh & 3;
  int kb = t < 99 ? 99 - t : 0;
  for (int o = tid; o < 2080; o += 256) {
    float acc = 0.f;
    for (int k = 0; k < kb; ++k)
      acc += sc[k] * Vbuf[((size_t)bh * 99 + t + k) * 2080 + o];
    for (int k = kb; k < 100; ++k)
      acc += sc[k] * Vh[((size_t)bh * 512 + (t + k - 99)) * 2080 + o];
    int f = o >> 5, vd = o & 31;
    av[((size_t)(b * 512 + t) * 65 + f) * 128 + nh * 32 + vd] = acc * rscale;
  }
}

// ---------------- P projection + PReLU ----------------
__global__ __launch_bounds__(256) void k_pproj(
    const float* __restrict__ av, const float* __restrict__ pw,
    const float* __restrict__ pb, const float* __restrict__ pa,
    float* __restrict__ ph) {
  __shared__ float avs[8320];
  int n = blockIdx.x, tid = threadIdx.x;
  for (int e = tid; e < 8320; e += 256) avs[e] = av[(size_t)n * 8320 + e];
  __syncthreads();
  int o = tid & 127, g = tid >> 7;
  float a = pa[0], bias = pb[o];
  const float4* w4 = (const float4*)(pw + (size_t)o * 128);
  for (int f = g; f < 65; f += 2) {
    float acc = bias;
    const float4* xr = (const float4*)&avs[f * 128];
    #pragma unroll
    for (int kk = 0; kk < 32; ++kk) {
      float4 w = w4[kk], xv = xr[kk];
      acc += w.x * xv.x + w.y * xv.y + w.z * xv.z + w.w * xv.w;
    }
    acc = acc >= 0.f ? acc : a * acc;
    ph[(size_t)n * 8320 + f * 128 + o] = acc;
  }
}

// ---------------- final LN(8320) + residual -> fp32 out ----------------
__global__ __launch_bounds__(256) void k_lnfinal(
    const float* __restrict__ ph, const float* __restrict__ plg,
    const float* __restrict__ plb, const float* __restrict__ inter,
    float* __restrict__ out) {
  __shared__ float rs[4], rq[4];
  int n = blockIdx.x, tid = threadIdx.x;
  const float* p = ph + (size_t)n * 8320;
  float s = 0.f, q = 0.f;
  for (int e = tid; e < 8320; e += 256) { float v = p[e]; s += v; q += v * v; }
  wavered2(s, q);
  if ((tid & 63) == 0) { rs[tid >> 6] = s; rq[tid >> 6] = q; }
  __syncthreads();
  float S = rs[0] + rs[1] + rs[2] + rs[3];
  float Q = rq[0] + rq[1] + rq[2] + rq[3];
  float mu = S / 8320.f;
  float rinv = rsqrtf(fmaxf(Q / 8320.f - mu * mu, 0.f) + 1e-5f);
  for (int e = tid; e < 8320; e += 256) {
    out[(size_t)n * 8320 + e] =
        (p[e] - mu) * rinv * plg[e] + plb[e] + inter[(size_t)n * 8320 + e];
  }
}

extern "C" void kernel_launch(void* const* d_in, const int* in_sizes, int n_in,
                              void* d_out, int out_size, void* d_ws, size_t ws_size,
                              hipStream_t stream) {
  const float* x       = (const float*)d_in[0];
  const float* conv_w  = (const float*)d_in[1];
  const float* conv_b  = (const float*)d_in[2];
  const float* conv_a  = (const float*)d_in[3];
  const float* ln0_g   = (const float*)d_in[4];
  const float* ln0_b   = (const float*)d_in[5];
  const float* iwih_f  = (const float*)d_in[6];
  const float* iwhh_f  = (const float*)d_in[7];
  const float* ibih_f  = (const float*)d_in[8];
  const float* ibhh_f  = (const float*)d_in[9];
  const float* iwih_r  = (const float*)d_in[10];
  const float* iwhh_r  = (const float*)d_in[11];
  const float* ibih_r  = (const float*)d_in[12];
  const float* ibhh_r  = (const float*)d_in[13];
  const float* deconv_w= (const float*)d_in[14];
  const float* deconv_b= (const float*)d_in[15];
  const float* ln1_g   = (const float*)d_in[16];
  const float* ln1_b   = (const float*)d_in[17];
  const float* wih     = (const float*)d_in[18];
  const float* whh     = (const float*)d_in[19];
  const float* bih     = (const float*)d_in[20];
  const float* bhh     = (const float*)d_in[21];
  const float* lin_w   = (const float*)d_in[22];
  const float* lin_b   = (const float*)d_in[23];
  const float* q_w     = (const float*)d_in[24];
  const float* q_b     = (const float*)d_in[25];
  const float* q_a     = (const float*)d_in[26];
  const float* q_lg    = (const float*)d_in[27];
  const float* q_lb    = (const float*)d_in[28];
  const float* k_w     = (const float*)d_in[29];
  const float* k_b     = (const float*)d_in[30];
  const float* k_a     = (const float*)d_in[31];
  const float* k_lg    = (const float*)d_in[32];
  const float* k_lb    = (const float*)d_in[33];
  const float* v_w     = (const float*)d_in[34];
  const float* v_b     = (const float*)d_in[35];
  const float* v_a     = (const float*)d_in[36];
  const float* v_lg    = (const float*)d_in[37];
  const float* v_lb    = (const float*)d_in[38];
  const float* p_w     = (const float*)d_in[39];
  const float* p_b     = (const float*)d_in[40];
  const float* p_a     = (const float*)d_in[41];
  const float* p_lg    = (const float*)d_in[42];
  const float* p_lb    = (const float*)d_in[43];
  const float* K_buf   = (const float*)d_in[44];
  const float* V_buf   = (const float*)d_in[45];
  const float* h0v     = (const float*)d_in[46];
  const float* c0v     = (const float*)d_in[47];

  char* ws = (char*)d_ws;
  float* hc    = (float*)(ws + OFF_A);
  float* yfb   = (float*)(ws + OFF_A + 16777216ULL);
  float* yrb   = (float*)(ws + OFF_DE);
  float* ln1y  = (float*)(ws + OFF_A);
  float* Vh    = (float*)(ws + OFF_A);
  float* phb   = (float*)(ws + OFF_A);
  float* intra = (float*)(ws + OFF_B);
  float* avb   = (float*)(ws + OFF_B);
  float* inter = (float*)(ws + OFF_C);
  float* Qh    = (float*)(ws + OFF_DE);
  float* Kh    = (float*)(ws + OFF_DE + 17039360ULL);
  float* wT    = (float*)(ws + OFF_WT);
  float* wiTf = wT + 0;        // 131072 floats
  float* whTf = wT + 131072;   // 262144
  float* wiTr = wT + 393216;   // 131072
  float* whTr = wT + 524288;   // 262144 -> ends at 786432 floats (3 MB)
  u16* wiTb = (u16*)(wT + 786432);      // 131072 u16 (256 KB)
  u16* whTb = wiTb + 131072;            // 262144 u16 (512 KB)
  u16* lwb  = whTb + 262144;            // 32768 u16 (64 KB)

  k_transpose_ff<<<512, 256, 0, stream>>>(iwih_f, wiTf, 1024, 128);
  k_transpose_ff<<<1024, 256, 0, stream>>>(iwhh_f, whTf, 1024, 256);
  k_transpose_ff<<<512, 256, 0, stream>>>(iwih_r, wiTr, 1024, 128);
  k_transpose_ff<<<1024, 256, 0, stream>>>(iwhh_r, whTr, 1024, 256);
  k_transpose_fb<<<512, 256, 0, stream>>>(wih, wiTb, 1024, 128);
  k_transpose_fb<<<1024, 256, 0, stream>>>(whh, whTb, 1024, 256);
  k_cast_fb<<<128, 256, 0, stream>>>(lin_w, lwb, 32768);

  k_conv_ln0<<<2048, 256, 0, stream>>>(x, conv_w, conv_b, conv_a, ln0_g, ln0_b, hc);
  k_intra_lstm<<<512, 256, 0, stream>>>(hc, wiTf, whTf, ibih_f, ibhh_f,
                                        wiTr, whTr, ibih_r, ibhh_r, yfb, yrb);
  k_deconv<<<2048, 256, 0, stream>>>(yfb, yrb, deconv_w, deconv_b, x, intra);
  k_ln1<<<2048, 256, 0, stream>>>(intra, ln1_g, ln1_b, ln1y);
  k_inter_lstm<<<130, 1024, 0, stream>>>(ln1y, wiTb, whTb, bih, bhh,
                                         lwb, lin_b, h0v, c0v, intra, inter);
  k_qkv<<<2048, 256, 0, stream>>>(inter, q_w, q_b, q_a, k_w, k_b, k_a,
                                  v_w, v_b, v_a, Qh, Kh, Vh);
  k_lnrow<<<8192, 256, 0, stream>>>(Qh, 520, q_lg, q_lb);
  k_lnrow<<<8192, 256, 0, stream>>>(Kh, 520, k_lg, k_lb);
  k_lnrow<<<8192, 256, 0, stream>>>(Vh, 2080, v_lg, v_lb);
  k_attn<<<8192, 256, 0, stream>>>(Qh, Kh, Vh, K_buf, V_buf, avb);
  k_pproj<<<2048, 256, 0, stream>>>(avb, p_w, p_b, p_a, phb);
  k_lnfinal<<<2048, 256, 0, stream>>>(phb, p_lg, p_lb, inter, (float*)d_out);
}